// Round 1
// baseline (583.978 us; speedup 1.0000x reference)
//
#include <hip/hip_runtime.h>
#include <hip/hip_bf16.h>
#include <math.h>

#define BATCHN  16
#define SEQ     1024
#define DMODEL  256
#define DSTATE  128
#define HEADDIM 64
#define DINNER  512
#define NHEADS  8
#define CONVDIM 768
#define DINPROJ 1288
#define KCONV   4
#define NCHUNK  16
#define LCHUNK  64
#define EPSV    1e-5f
#define ROWS    (BATCHN*SEQ)   // 16384

// ---------------------------------------------------------------- GEMM f32
// C[M,N] = A[M,K] @ B[K,N], tiles 64x64x16, 256 threads, 4x4 per thread.
template<int BM, int BN, int BK>
__global__ __launch_bounds__(256) void gemm_f32(const float* __restrict__ A,
                                                const float* __restrict__ Bm,
                                                float* __restrict__ C,
                                                int M, int N, int K) {
    __shared__ float As[BK][BM + 1];
    __shared__ float Bs[BK][BN + 1];
    const int tid  = threadIdx.x;
    const int row0 = blockIdx.y * BM;
    const int col0 = blockIdx.x * BN;
    const int tx = tid & 15, ty = tid >> 4;
    const bool fullN = (col0 + BN) <= N;
    float acc[4][4] = {};
    for (int k0 = 0; k0 < K; k0 += BK) {
        {   // A tile: BM x BK  (1024 floats = 256 float4)
            int r = tid >> 2, kq = tid & 3;
            const float4 v = *reinterpret_cast<const float4*>(
                &A[(size_t)(row0 + r) * K + k0 + kq * 4]);
            As[kq*4+0][r] = v.x; As[kq*4+1][r] = v.y;
            As[kq*4+2][r] = v.z; As[kq*4+3][r] = v.w;
        }
        {   // B tile: BK x BN
            int kk = tid >> 4, cq = tid & 15;
            if (fullN) {
                const float4 v = *reinterpret_cast<const float4*>(
                    &Bm[(size_t)(k0 + kk) * N + col0 + cq * 4]);
                Bs[kk][cq*4+0] = v.x; Bs[kk][cq*4+1] = v.y;
                Bs[kk][cq*4+2] = v.z; Bs[kk][cq*4+3] = v.w;
            } else {
                #pragma unroll
                for (int j = 0; j < 4; ++j) {
                    int cc = col0 + cq * 4 + j;
                    Bs[kk][cq*4+j] = (cc < N) ? Bm[(size_t)(k0 + kk) * N + cc] : 0.f;
                }
            }
        }
        __syncthreads();
        #pragma unroll
        for (int kk = 0; kk < BK; ++kk) {
            float a[4], b[4];
            #pragma unroll
            for (int i = 0; i < 4; ++i) a[i] = As[kk][ty*4+i];
            #pragma unroll
            for (int j = 0; j < 4; ++j) b[j] = Bs[kk][tx*4+j];
            #pragma unroll
            for (int i = 0; i < 4; ++i)
                #pragma unroll
                for (int j = 0; j < 4; ++j) acc[i][j] += a[i]*b[j];
        }
        __syncthreads();
    }
    #pragma unroll
    for (int i = 0; i < 4; ++i) {
        int r = row0 + ty*4 + i;
        #pragma unroll
        for (int j = 0; j < 4; ++j) {
            int cc = col0 + tx*4 + j;
            if (cc < N) C[(size_t)r * N + cc] = acc[i][j];
        }
    }
}

// ------------------------------------------------- depthwise conv + SiLU
__global__ void conv_silu_k(const float* __restrict__ zx,
                            const float* __restrict__ cw,
                            const float* __restrict__ cb,
                            float* __restrict__ out) {
    int idx = blockIdx.x * blockDim.x + threadIdx.x;
    const int total = ROWS * CONVDIM;
    const int stride = gridDim.x * blockDim.x;
    for (; idx < total; idx += stride) {
        int c  = idx % CONVDIM;
        int bt = idx / CONVDIM;
        int t  = bt & (SEQ - 1);
        float acc = cb[c];
        #pragma unroll
        for (int k = 0; k < KCONV; ++k) {
            int tt = t - (KCONV - 1) + k;
            if (tt >= 0)
                acc += zx[(size_t)(bt - (KCONV - 1) + k) * DINPROJ + DINNER + c]
                       * cw[c * KCONV + k];
        }
        out[idx] = acc / (1.f + __expf(-acc));   // silu
    }
}

// ------------------------------------------------------------- dt prep
__global__ void dt_prep_k(const float* __restrict__ zx,
                          const float* __restrict__ dt_bias,
                          const float* __restrict__ A_log,
                          float* __restrict__ dtb,
                          float* __restrict__ adtb) {
    int idx = blockIdx.x * blockDim.x + threadIdx.x;
    if (idx >= ROWS * NHEADS) return;
    int h  = idx % NHEADS;
    int bt = idx / NHEADS;
    float v  = zx[(size_t)bt * DINPROJ + (DINNER + CONVDIM) + h] + dt_bias[h];
    float dt = (v > 20.f) ? v : log1pf(__expf(v));   // softplus
    float A  = -__expf(A_log[h]);
    dtb[idx]  = dt;
    adtb[idx] = dt * A;
}

// -------------------------------------------------- SSD per-(b,chunk) kernel
// Computes: G=C·B^T, per-head masked-decay scores, Y_diag + D*x, chunk states.
__global__ __launch_bounds__(256) void ssd_chunk_k(const float* __restrict__ xbc,
                                                   const float* __restrict__ dtb,
                                                   const float* __restrict__ adtb,
                                                   const float* __restrict__ Dp,
                                                   float* __restrict__ ybuf,
                                                   float* __restrict__ states,
                                                   float* __restrict__ acsbuf,
                                                   float* __restrict__ chunksum) {
    const int c = blockIdx.x, b = blockIdx.y;
    const int row0 = b * SEQ + c * LCHUNK;
    const int tid  = threadIdx.x;
    __shared__ float Bs[LCHUNK][DSTATE + 1];
    __shared__ float Cs[LCHUNK][DSTATE + 1];
    __shared__ float G [LCHUNK][LCHUNK + 1];
    __shared__ float Xs[LCHUNK][LCHUNK + 1];
    __shared__ float Ps[LCHUNK][LCHUNK + 1];
    __shared__ float acs_s[NHEADS][LCHUNK];

    // per-head cumsum of dt*A over the chunk (8 threads, serial 64)
    if (tid < NHEADS) {
        float s = 0.f;
        for (int l = 0; l < LCHUNK; ++l) {
            s += adtb[(size_t)(row0 + l) * NHEADS + tid];
            acs_s[tid][l] = s;
            acsbuf[(((size_t)b * NCHUNK + c) * NHEADS + tid) * LCHUNK + l] = s;
        }
        chunksum[((size_t)b * NCHUNK + c) * NHEADS + tid] = s;
    }
    // stage B (cols 512..639) and C (cols 640..767): 2048 float4 each half
    for (int i = 0; i < 8; ++i) {
        int idx = tid + i * 256;      // 0..2047
        int l = idx >> 5, q = idx & 31;
        const float* rowp = &xbc[(size_t)(row0 + l) * CONVDIM + DINNER];
        float4 vb = *reinterpret_cast<const float4*>(rowp + q * 4);
        Bs[l][q*4+0] = vb.x; Bs[l][q*4+1] = vb.y; Bs[l][q*4+2] = vb.z; Bs[l][q*4+3] = vb.w;
        float4 vc = *reinterpret_cast<const float4*>(rowp + DSTATE + q * 4);
        Cs[l][q*4+0] = vc.x; Cs[l][q*4+1] = vc.y; Cs[l][q*4+2] = vc.z; Cs[l][q*4+3] = vc.w;
    }
    __syncthreads();

    const int tx = tid & 15, ty = tid >> 4;
    {   // G[l][s] = sum_n C[l,n] * B[s,n]
        float acc[4][4] = {};
        for (int n = 0; n < DSTATE; ++n) {
            float cv[4], bv[4];
            #pragma unroll
            for (int i = 0; i < 4; ++i) cv[i] = Cs[ty*4+i][n];
            #pragma unroll
            for (int j = 0; j < 4; ++j) bv[j] = Bs[tx*4+j][n];
            #pragma unroll
            for (int i = 0; i < 4; ++i)
                #pragma unroll
                for (int j = 0; j < 4; ++j) acc[i][j] += cv[i]*bv[j];
        }
        #pragma unroll
        for (int i = 0; i < 4; ++i)
            #pragma unroll
            for (int j = 0; j < 4; ++j) G[ty*4+i][tx*4+j] = acc[i][j];
    }

    for (int h = 0; h < NHEADS; ++h) {
        __syncthreads();   // previous head fully done (also covers G on h=0)
        // X[l][p] = x * dt
        for (int i = 0; i < 16; ++i) {
            int idx = tid + i * 256;           // 4096
            int l = idx >> 6, p = idx & 63;
            Xs[l][p] = xbc[(size_t)(row0 + l) * CONVDIM + h * HEADDIM + p]
                       * dtb[(size_t)(row0 + l) * NHEADS + h];
        }
        // P[l][s] = (s<=l) ? G*exp(acs_l - acs_s) : 0
        #pragma unroll
        for (int i = 0; i < 4; ++i)
            #pragma unroll
            for (int j = 0; j < 4; ++j) {
                int l = ty*4+i, s = tx*4+j;
                Ps[l][s] = (s <= l) ? G[l][s] * __expf(acs_s[h][l] - acs_s[h][s]) : 0.f;
            }
        __syncthreads();
        {   // Y_diag[l][p] = P @ X  (+ D*x), write to ybuf
            float acc[4][4] = {};
            for (int s = 0; s < LCHUNK; ++s) {
                float av[4], bv[4];
                #pragma unroll
                for (int i = 0; i < 4; ++i) av[i] = Ps[ty*4+i][s];
                #pragma unroll
                for (int j = 0; j < 4; ++j) bv[j] = Xs[s][tx*4+j];
                #pragma unroll
                for (int i = 0; i < 4; ++i)
                    #pragma unroll
                    for (int j = 0; j < 4; ++j) acc[i][j] += av[i]*bv[j];
            }
            #pragma unroll
            for (int i = 0; i < 4; ++i) {
                int l = ty*4+i;
                #pragma unroll
                for (int j = 0; j < 4; ++j) {
                    int p = tx*4+j;
                    float xraw = xbc[(size_t)(row0 + l) * CONVDIM + h * HEADDIM + p];
                    ybuf[(size_t)(row0 + l) * DINNER + h * HEADDIM + p]
                        = acc[i][j] + Dp[h] * xraw;
                }
            }
        }
        __syncthreads();
        // Xd[l][p] = exp(acs[63]-acs[l]) * X[l][p]  (into Ps)
        for (int i = 0; i < 16; ++i) {
            int idx = tid + i * 256;
            int l = idx >> 6, p = idx & 63;
            Ps[l][p] = __expf(acs_s[h][LCHUNK-1] - acs_s[h][l]) * Xs[l][p];
        }
        __syncthreads();
        {   // states[h][p][n] = sum_l Xd[l][p] * B[l][n]
            int ni = tid & 15, pi = tid >> 4;
            float acc[4][8] = {};
            for (int l = 0; l < LCHUNK; ++l) {
                float xv[4], bv[8];
                #pragma unroll
                for (int i = 0; i < 4; ++i) xv[i] = Ps[l][pi*4+i];
                #pragma unroll
                for (int j = 0; j < 8; ++j) bv[j] = Bs[l][ni*8+j];
                #pragma unroll
                for (int i = 0; i < 4; ++i)
                    #pragma unroll
                    for (int j = 0; j < 8; ++j) acc[i][j] += xv[i]*bv[j];
            }
            float* sb = states + ((((size_t)b * NCHUNK + c) * NHEADS + h) * HEADDIM) * DSTATE;
            #pragma unroll
            for (int i = 0; i < 4; ++i)
                #pragma unroll
                for (int j = 0; j < 8; ++j)
                    sb[(size_t)(pi*4+i) * DSTATE + ni*8+j] = acc[i][j];
        }
    }
}

// ------------------------------------- inter-chunk sequential state scan
// In-place: states[b,c] <- prefix state BEFORE chunk c.
__global__ __launch_bounds__(256) void scan_k(float* __restrict__ states,
                                              const float* __restrict__ chunksum) {
    const int bh = blockIdx.x;           // B*H = 128
    const int b = bh >> 3, h = bh & 7;
    const int tid = threadIdx.x;
    float pref[32];
    #pragma unroll
    for (int k = 0; k < 32; ++k) pref[k] = 0.f;
    for (int c = 0; c < NCHUNK; ++c) {
        float* base = states + ((((size_t)b * NCHUNK + c) * NHEADS + h) * HEADDIM) * DSTATE;
        float dec = __expf(chunksum[((size_t)b * NCHUNK + c) * NHEADS + h]);
        #pragma unroll
        for (int k = 0; k < 32; ++k) {
            int idx = tid + k * 256;     // 8192 elems
            float cur = base[idx];
            base[idx] = pref[k];
            pref[k] = dec * pref[k] + cur;
        }
    }
}

// ------------------------------------------------- Y_off += C @ S * exp(acs)
__global__ __launch_bounds__(256) void yoff_k(const float* __restrict__ xbc,
                                              const float* __restrict__ states,
                                              const float* __restrict__ acsbuf,
                                              float* __restrict__ ybuf) {
    const int c = blockIdx.x, b = blockIdx.y;
    const int row0 = b * SEQ + c * LCHUNK;
    const int tid  = threadIdx.x;
    __shared__ float Cs[LCHUNK][DSTATE + 1];
    __shared__ float Ss[HEADDIM][DSTATE + 1];
    __shared__ float ea[LCHUNK];

    for (int i = 0; i < 8; ++i) {       // stage C
        int idx = tid + i * 256;
        int l = idx >> 5, q = idx & 31;
        float4 vc = *reinterpret_cast<const float4*>(
            &xbc[(size_t)(row0 + l) * CONVDIM + DINNER + DSTATE + q * 4]);
        Cs[l][q*4+0] = vc.x; Cs[l][q*4+1] = vc.y; Cs[l][q*4+2] = vc.z; Cs[l][q*4+3] = vc.w;
    }
    const int tx = tid & 15, ty = tid >> 4;
    for (int h = 0; h < NHEADS; ++h) {
        __syncthreads();                 // prev head compute done
        const float* sb = states + ((((size_t)b * NCHUNK + c) * NHEADS + h) * HEADDIM) * DSTATE;
        for (int i = 0; i < 8; ++i) {   // stage S (p x n)
            int idx = tid + i * 256;
            int p = idx >> 5, q = idx & 31;
            float4 v = *reinterpret_cast<const float4*>(&sb[(size_t)p * DSTATE + q * 4]);
            Ss[p][q*4+0] = v.x; Ss[p][q*4+1] = v.y; Ss[p][q*4+2] = v.z; Ss[p][q*4+3] = v.w;
        }
        if (tid < LCHUNK)
            ea[tid] = __expf(acsbuf[(((size_t)b * NCHUNK + c) * NHEADS + h) * LCHUNK + tid]);
        __syncthreads();
        float acc[4][4] = {};
        for (int n = 0; n < DSTATE; ++n) {
            float cv[4], sv[4];
            #pragma unroll
            for (int i = 0; i < 4; ++i) cv[i] = Cs[ty*4+i][n];
            #pragma unroll
            for (int j = 0; j < 4; ++j) sv[j] = Ss[tx*4+j][n];
            #pragma unroll
            for (int i = 0; i < 4; ++i)
                #pragma unroll
                for (int j = 0; j < 4; ++j) acc[i][j] += cv[i]*sv[j];
        }
        #pragma unroll
        for (int i = 0; i < 4; ++i) {
            int l = ty*4+i;
            #pragma unroll
            for (int j = 0; j < 4; ++j) {
                int p = tx*4+j;
                ybuf[(size_t)(row0 + l) * DINNER + h * HEADDIM + p] += acc[i][j] * ea[l];
            }
        }
    }
}

// ----------------------------------------- gate (silu(z)) + RMSNorm in place
__global__ __launch_bounds__(256) void gate_norm_k(float* __restrict__ ybuf,
                                                   const float* __restrict__ zx,
                                                   const float* __restrict__ nw) {
    const int row  = blockIdx.x * 4 + (threadIdx.x >> 6);
    const int lane = threadIdx.x & 63;
    float g[8];
    float ss = 0.f;
    #pragma unroll
    for (int j = 0; j < 8; ++j) {
        int cidx = j * 64 + lane;
        float y = ybuf[(size_t)row * DINNER + cidx];
        float z = zx[(size_t)row * DINPROJ + cidx];
        float sz = z / (1.f + __expf(-z));
        g[j] = y * sz;
        ss += g[j] * g[j];
    }
    #pragma unroll
    for (int off = 32; off; off >>= 1) ss += __shfl_xor(ss, off);
    float r = rsqrtf(ss / (float)DINNER + EPSV);
    #pragma unroll
    for (int j = 0; j < 8; ++j) {
        int cidx = j * 64 + lane;
        ybuf[(size_t)row * DINNER + cidx] = g[j] * r * nw[cidx];
    }
}

// ---------------------------------------------------------------- launch
extern "C" void kernel_launch(void* const* d_in, const int* in_sizes, int n_in,
                              void* d_out, int out_size, void* d_ws, size_t ws_size,
                              hipStream_t stream) {
    const float* u       = (const float*)d_in[0];
    const float* W_in    = (const float*)d_in[1];
    const float* conv_w  = (const float*)d_in[2];
    const float* conv_b  = (const float*)d_in[3];
    const float* dt_bias = (const float*)d_in[4];
    const float* A_log   = (const float*)d_in[5];
    const float* Dp      = (const float*)d_in[6];
    const float* norm_w  = (const float*)d_in[7];
    const float* W_out   = (const float*)d_in[8];
    float* out = (float*)d_out;

    char* p = (char*)d_ws;
    float* zx       = (float*)p; p += (size_t)ROWS * DINPROJ * sizeof(float);   // 84.4 MB
    float* xbc      = (float*)p; p += (size_t)ROWS * CONVDIM * sizeof(float);   // 50.3 MB
    float* dtb      = (float*)p; p += (size_t)ROWS * NHEADS  * sizeof(float);
    float* adtb     = (float*)p; p += (size_t)ROWS * NHEADS  * sizeof(float);
    float* chunksum = (float*)p; p += (size_t)BATCHN * NCHUNK * NHEADS * sizeof(float);
    float* acsbuf   = (float*)p; p += (size_t)BATCHN * NCHUNK * NHEADS * LCHUNK * sizeof(float);
    float* states   = (float*)p; p += (size_t)BATCHN * NCHUNK * NHEADS * HEADDIM * DSTATE * sizeof(float); // 67 MB
    float* ybuf     = (float*)p; p += (size_t)ROWS * DINNER * sizeof(float);    // 33.5 MB

    // 1. in_proj: zx = u @ W_in   (16384x1288, K=256)
    gemm_f32<64,64,16><<<dim3((DINPROJ + 63)/64, ROWS/64), 256, 0, stream>>>(
        u, W_in, zx, ROWS, DINPROJ, DMODEL);
    // 2. depthwise conv + silu
    conv_silu_k<<<4096, 256, 0, stream>>>(zx, conv_w, conv_b, xbc);
    // 3. dt softplus + A*dt
    dt_prep_k<<<(ROWS*NHEADS + 255)/256, 256, 0, stream>>>(zx, dt_bias, A_log, dtb, adtb);
    // 4. per-chunk SSD: Y_diag + D*x, chunk states
    ssd_chunk_k<<<dim3(NCHUNK, BATCHN), 256, 0, stream>>>(
        xbc, dtb, adtb, Dp, ybuf, states, acsbuf, chunksum);
    // 5. inter-chunk state scan (in place -> prefix states)
    scan_k<<<BATCHN*NHEADS, 256, 0, stream>>>(states, chunksum);
    // 6. Y_off += C @ S_prefix * exp(acs)
    yoff_k<<<dim3(NCHUNK, BATCHN), 256, 0, stream>>>(xbc, states, acsbuf, ybuf);
    // 7. gate + RMSNorm (in place on ybuf)
    gate_norm_k<<<ROWS/4, 256, 0, stream>>>(ybuf, zx, norm_w);
    // 8. out_proj: out = g @ W_out  (16384x256, K=512)
    gemm_f32<64,64,16><<<dim3(DMODEL/64, ROWS/64), 256, 0, stream>>>(
        ybuf, W_out, out, ROWS, DMODEL, DINNER);
}

// Round 2
// 348.278 us; speedup vs baseline: 1.6768x; 1.6768x over previous
//
#include <hip/hip_runtime.h>
#include <hip/hip_bf16.h>
#include <math.h>

#define BATCHN  16
#define SEQ     1024
#define DMODEL  256
#define DSTATE  128
#define HEADDIM 64
#define DINNER  512
#define NHEADS  8
#define CONVDIM 768
#define DINPROJ 1288
#define ZXLD    1280       // zx workspace stride (z + xBC only; dt handled separately)
#define KCONV   4
#define NCHUNK  16
#define LCHUNK  64
#define EPSV    1e-5f
#define ROWS    (BATCHN*SEQ)   // 16384

typedef __attribute__((ext_vector_type(8))) __bf16 bf16x8;
typedef __attribute__((ext_vector_type(4))) float  f32x4;

__device__ inline ushort f2bf(float f) {
    union { float f; uint32_t u; } v; v.f = f;
    uint32_t r = v.u + 0x7fff + ((v.u >> 16) & 1);   // RNE
    return (ushort)(r >> 16);
}
__device__ inline uint4 pack8(float4 a, float4 b) {
    uint4 r;
    r.x = (uint32_t)f2bf(a.x) | ((uint32_t)f2bf(a.y) << 16);
    r.y = (uint32_t)f2bf(a.z) | ((uint32_t)f2bf(a.w) << 16);
    r.z = (uint32_t)f2bf(b.x) | ((uint32_t)f2bf(b.y) << 16);
    r.w = (uint32_t)f2bf(b.z) | ((uint32_t)f2bf(b.w) << 16);
    return r;
}

// ---------------------------------------------- W transpose + cast to bf16
// dst[N][K] (bf16) = src[K][col0+n]  (f32), tile 32x32 via LDS
__global__ __launch_bounds__(256) void transpose_cast_k(const float* __restrict__ src,
                                                        ushort* __restrict__ dst,
                                                        int K, int ldsrc, int col0) {
    __shared__ float Ts[32][33];
    const int tx = threadIdx.x & 31, ty = threadIdx.x >> 5;   // ty 0..7
    const int n0 = blockIdx.x * 32, k0 = blockIdx.y * 32;
    #pragma unroll
    for (int j = 0; j < 4; ++j) {
        int kl = ty * 4 + j;
        Ts[kl][tx] = src[(size_t)(k0 + kl) * ldsrc + col0 + n0 + tx];
    }
    __syncthreads();
    #pragma unroll
    for (int j = 0; j < 4; ++j) {
        int nl = ty * 4 + j;
        dst[(size_t)(n0 + nl) * K + k0 + tx] = f2bf(Ts[tx][nl]);
    }
}

// ------------------------------------------------------- bf16 MFMA GEMM
// C[M,N](f32) = A[M,K](f32, cast to bf16) @ Bt[N,K](bf16, pre-transposed)
// 128x128 block, BK=32, 4 waves of 64x64, mfma_f32_16x16x32_bf16.
#define LDSW 40   // padded LDS row stride (ushorts), 16B-aligned, ~2-way banks
__global__ __launch_bounds__(256) void gemm_bf16(const float* __restrict__ A,
                                                 const ushort* __restrict__ Bt,
                                                 float* __restrict__ C,
                                                 int M, int N, int K) {
    __shared__ ushort As[128 * LDSW];
    __shared__ ushort Bs[128 * LDSW];
    const int tid  = threadIdx.x;
    const int m0 = blockIdx.y * 128, n0 = blockIdx.x * 128;
    const int wid = tid >> 6, lane = tid & 63;
    const int wr = wid >> 1, wc = wid & 1;
    const int r = tid >> 1, kq = tid & 1;          // staging: row, k-half
    const int fr = lane & 15, kc = lane >> 4;      // fragment row / k-chunk

    f32x4 acc[4][4];
    #pragma unroll
    for (int i = 0; i < 4; ++i)
        #pragma unroll
        for (int j = 0; j < 4; ++j) acc[i][j] = (f32x4)0.f;

    for (int kt = 0; kt < K; kt += 32) {
        // --- stage A (f32 -> bf16)
        const float* ap = &A[(size_t)(m0 + r) * K + kt + kq * 16];
        float4 v0 = *(const float4*)(ap + 0);
        float4 v1 = *(const float4*)(ap + 4);
        float4 v2 = *(const float4*)(ap + 8);
        float4 v3 = *(const float4*)(ap + 12);
        *(uint4*)&As[r * LDSW + kq * 16]     = pack8(v0, v1);
        *(uint4*)&As[r * LDSW + kq * 16 + 8] = pack8(v2, v3);
        // --- stage B (already bf16)
        const ushort* bp = &Bt[(size_t)(n0 + r) * K + kt + kq * 16];
        *(uint4*)&Bs[r * LDSW + kq * 16]     = *(const uint4*)(bp);
        *(uint4*)&Bs[r * LDSW + kq * 16 + 8] = *(const uint4*)(bp + 8);
        __syncthreads();
        // --- fragments + MFMA
        bf16x8 af[4], bfv[4];
        #pragma unroll
        for (int i = 0; i < 4; ++i) {
            af[i]  = *(const bf16x8*)&As[(wr * 64 + i * 16 + fr) * LDSW + kc * 8];
            bfv[i] = *(const bf16x8*)&Bs[(wc * 64 + i * 16 + fr) * LDSW + kc * 8];
        }
        #pragma unroll
        for (int i = 0; i < 4; ++i)
            #pragma unroll
            for (int j = 0; j < 4; ++j)
                acc[i][j] = __builtin_amdgcn_mfma_f32_16x16x32_bf16(af[i], bfv[j], acc[i][j], 0, 0, 0);
        __syncthreads();
    }
    // --- epilogue: D row = (lane>>4)*4 + q, col = lane&15  (m89-verified)
    #pragma unroll
    for (int i = 0; i < 4; ++i)
        #pragma unroll
        for (int j = 0; j < 4; ++j)
            #pragma unroll
            for (int q = 0; q < 4; ++q) {
                int rr = m0 + wr * 64 + i * 16 + (lane >> 4) * 4 + q;
                int cc = n0 + wc * 64 + j * 16 + (lane & 15);
                C[(size_t)rr * N + cc] = acc[i][j][q];
            }
}

// ------------------------------------------------- dt path: exact f32 GEMV
// dt_raw[bt][h] = u[bt,:] . W_in[:,1280+h];  dtb = softplus(+bias); adtb = dt*A
__global__ __launch_bounds__(256) void dt_fused_k(const float* __restrict__ u,
                                                  const float* __restrict__ W_in,
                                                  const float* __restrict__ dt_bias,
                                                  const float* __restrict__ A_log,
                                                  float* __restrict__ dtb,
                                                  float* __restrict__ adtb) {
    __shared__ float Ws[DMODEL][NHEADS];
    const int tid = threadIdx.x;
    #pragma unroll
    for (int j = 0; j < 8; ++j) {
        int idx = tid + j * 256;
        Ws[idx >> 3][idx & 7] = W_in[(size_t)(idx >> 3) * DINPROJ + 1280 + (idx & 7)];
    }
    __syncthreads();
    const int lane = tid & 63, w = tid >> 6;
    const int h = lane & 7;
    const int row = blockIdx.x * 32 + w * 8 + (lane >> 3);
    const float* up = &u[(size_t)row * DMODEL];
    float acc = 0.f;
    for (int k = 0; k < DMODEL; k += 4) {
        float4 uv = *(const float4*)(up + k);
        acc += uv.x * Ws[k][h] + uv.y * Ws[k+1][h] + uv.z * Ws[k+2][h] + uv.w * Ws[k+3][h];
    }
    float v = acc + dt_bias[h];
    float dt = (v > 20.f) ? v : log1pf(__expf(v));
    dtb [(size_t)row * NHEADS + h] = dt;
    adtb[(size_t)row * NHEADS + h] = dt * (-__expf(A_log[h]));
}

// ------------------------------------------------- depthwise conv + SiLU
__global__ void conv_silu_k(const float* __restrict__ zx,
                            const float* __restrict__ cw,
                            const float* __restrict__ cb,
                            float* __restrict__ out) {
    int idx = blockIdx.x * blockDim.x + threadIdx.x;
    const int total = ROWS * CONVDIM;
    const int stride = gridDim.x * blockDim.x;
    for (; idx < total; idx += stride) {
        int c  = idx % CONVDIM;
        int bt = idx / CONVDIM;
        int t  = bt & (SEQ - 1);
        float acc = cb[c];
        #pragma unroll
        for (int k = 0; k < KCONV; ++k) {
            int tt = t - (KCONV - 1) + k;
            if (tt >= 0)
                acc += zx[(size_t)(bt - (KCONV - 1) + k) * ZXLD + DINNER + c]
                       * cw[c * KCONV + k];
        }
        out[idx] = acc / (1.f + __expf(-acc));   // silu
    }
}

// -------------------------------------------------- SSD per-(b,chunk) kernel
__global__ __launch_bounds__(256) void ssd_chunk_k(const float* __restrict__ xbc,
                                                   const float* __restrict__ dtb,
                                                   const float* __restrict__ adtb,
                                                   const float* __restrict__ Dp,
                                                   float* __restrict__ ybuf,
                                                   float* __restrict__ states,
                                                   float* __restrict__ acsbuf,
                                                   float* __restrict__ chunksum) {
    const int c = blockIdx.x, b = blockIdx.y;
    const int row0 = b * SEQ + c * LCHUNK;
    const int tid  = threadIdx.x;
    __shared__ float Bs[LCHUNK][DSTATE + 1];
    __shared__ float Cs[LCHUNK][DSTATE + 1];
    __shared__ float G [LCHUNK][LCHUNK + 1];
    __shared__ float Xs[LCHUNK][LCHUNK + 1];
    __shared__ float Ps[LCHUNK][LCHUNK + 1];
    __shared__ float acs_s[NHEADS][LCHUNK];

    if (tid < NHEADS) {
        float s = 0.f;
        for (int l = 0; l < LCHUNK; ++l) {
            s += adtb[(size_t)(row0 + l) * NHEADS + tid];
            acs_s[tid][l] = s;
            acsbuf[(((size_t)b * NCHUNK + c) * NHEADS + tid) * LCHUNK + l] = s;
        }
        chunksum[((size_t)b * NCHUNK + c) * NHEADS + tid] = s;
    }
    for (int i = 0; i < 8; ++i) {
        int idx = tid + i * 256;
        int l = idx >> 5, q = idx & 31;
        const float* rowp = &xbc[(size_t)(row0 + l) * CONVDIM + DINNER];
        float4 vb = *reinterpret_cast<const float4*>(rowp + q * 4);
        Bs[l][q*4+0] = vb.x; Bs[l][q*4+1] = vb.y; Bs[l][q*4+2] = vb.z; Bs[l][q*4+3] = vb.w;
        float4 vc = *reinterpret_cast<const float4*>(rowp + DSTATE + q * 4);
        Cs[l][q*4+0] = vc.x; Cs[l][q*4+1] = vc.y; Cs[l][q*4+2] = vc.z; Cs[l][q*4+3] = vc.w;
    }
    __syncthreads();

    const int tx = tid & 15, ty = tid >> 4;
    {   // G[l][s] = sum_n C[l,n] * B[s,n]
        float acc[4][4] = {};
        for (int n = 0; n < DSTATE; ++n) {
            float cv[4], bv[4];
            #pragma unroll
            for (int i = 0; i < 4; ++i) cv[i] = Cs[ty*4+i][n];
            #pragma unroll
            for (int j = 0; j < 4; ++j) bv[j] = Bs[tx*4+j][n];
            #pragma unroll
            for (int i = 0; i < 4; ++i)
                #pragma unroll
                for (int j = 0; j < 4; ++j) acc[i][j] += cv[i]*bv[j];
        }
        #pragma unroll
        for (int i = 0; i < 4; ++i)
            #pragma unroll
            for (int j = 0; j < 4; ++j) G[ty*4+i][tx*4+j] = acc[i][j];
    }

    for (int h = 0; h < NHEADS; ++h) {
        __syncthreads();
        for (int i = 0; i < 16; ++i) {
            int idx = tid + i * 256;
            int l = idx >> 6, p = idx & 63;
            Xs[l][p] = xbc[(size_t)(row0 + l) * CONVDIM + h * HEADDIM + p]
                       * dtb[(size_t)(row0 + l) * NHEADS + h];
        }
        #pragma unroll
        for (int i = 0; i < 4; ++i)
            #pragma unroll
            for (int j = 0; j < 4; ++j) {
                int l = ty*4+i, s = tx*4+j;
                Ps[l][s] = (s <= l) ? G[l][s] * __expf(acs_s[h][l] - acs_s[h][s]) : 0.f;
            }
        __syncthreads();
        {   // Y_diag = P @ X  (+ D*x)
            float acc[4][4] = {};
            for (int s = 0; s < LCHUNK; ++s) {
                float av[4], bv[4];
                #pragma unroll
                for (int i = 0; i < 4; ++i) av[i] = Ps[ty*4+i][s];
                #pragma unroll
                for (int j = 0; j < 4; ++j) bv[j] = Xs[s][tx*4+j];
                #pragma unroll
                for (int i = 0; i < 4; ++i)
                    #pragma unroll
                    for (int j = 0; j < 4; ++j) acc[i][j] += av[i]*bv[j];
            }
            #pragma unroll
            for (int i = 0; i < 4; ++i) {
                int l = ty*4+i;
                #pragma unroll
                for (int j = 0; j < 4; ++j) {
                    int p = tx*4+j;
                    float xraw = xbc[(size_t)(row0 + l) * CONVDIM + h * HEADDIM + p];
                    ybuf[(size_t)(row0 + l) * DINNER + h * HEADDIM + p]
                        = acc[i][j] + Dp[h] * xraw;
                }
            }
        }
        __syncthreads();
        for (int i = 0; i < 16; ++i) {
            int idx = tid + i * 256;
            int l = idx >> 6, p = idx & 63;
            Ps[l][p] = __expf(acs_s[h][LCHUNK-1] - acs_s[h][l]) * Xs[l][p];
        }
        __syncthreads();
        {   // states[h][p][n] = sum_l Xd[l][p] * B[l][n]
            int ni = tid & 15, pi = tid >> 4;
            float acc[4][8] = {};
            for (int l = 0; l < LCHUNK; ++l) {
                float xv[4], bv[8];
                #pragma unroll
                for (int i = 0; i < 4; ++i) xv[i] = Ps[l][pi*4+i];
                #pragma unroll
                for (int j = 0; j < 8; ++j) bv[j] = Bs[l][ni*8+j];
                #pragma unroll
                for (int i = 0; i < 4; ++i)
                    #pragma unroll
                    for (int j = 0; j < 8; ++j) acc[i][j] += xv[i]*bv[j];
            }
            float* sb = states + ((((size_t)b * NCHUNK + c) * NHEADS + h) * HEADDIM) * DSTATE;
            #pragma unroll
            for (int i = 0; i < 4; ++i)
                #pragma unroll
                for (int j = 0; j < 8; ++j)
                    sb[(size_t)(pi*4+i) * DSTATE + ni*8+j] = acc[i][j];
        }
    }
}

// ------------------------------------- inter-chunk sequential state scan
__global__ __launch_bounds__(256) void scan_k(float* __restrict__ states,
                                              const float* __restrict__ chunksum) {
    const int bh = blockIdx.x;
    const int b = bh >> 3, h = bh & 7;
    const int tid = threadIdx.x;
    float pref[32];
    #pragma unroll
    for (int k = 0; k < 32; ++k) pref[k] = 0.f;
    for (int c = 0; c < NCHUNK; ++c) {
        float* base = states + ((((size_t)b * NCHUNK + c) * NHEADS + h) * HEADDIM) * DSTATE;
        float dec = __expf(chunksum[((size_t)b * NCHUNK + c) * NHEADS + h]);
        #pragma unroll
        for (int k = 0; k < 32; ++k) {
            int idx = tid + k * 256;
            float cur = base[idx];
            base[idx] = pref[k];
            pref[k] = dec * pref[k] + cur;
        }
    }
}

// ------------------------------------------------- Y_off += C @ S * exp(acs)
__global__ __launch_bounds__(256) void yoff_k(const float* __restrict__ xbc,
                                              const float* __restrict__ states,
                                              const float* __restrict__ acsbuf,
                                              float* __restrict__ ybuf) {
    const int c = blockIdx.x, b = blockIdx.y;
    const int row0 = b * SEQ + c * LCHUNK;
    const int tid  = threadIdx.x;
    __shared__ float Cs[LCHUNK][DSTATE + 1];
    __shared__ float Ss[HEADDIM][DSTATE + 1];
    __shared__ float ea[LCHUNK];

    for (int i = 0; i < 8; ++i) {
        int idx = tid + i * 256;
        int l = idx >> 5, q = idx & 31;
        float4 vc = *reinterpret_cast<const float4*>(
            &xbc[(size_t)(row0 + l) * CONVDIM + DINNER + DSTATE + q * 4]);
        Cs[l][q*4+0] = vc.x; Cs[l][q*4+1] = vc.y; Cs[l][q*4+2] = vc.z; Cs[l][q*4+3] = vc.w;
    }
    const int tx = tid & 15, ty = tid >> 4;
    for (int h = 0; h < NHEADS; ++h) {
        __syncthreads();
        const float* sb = states + ((((size_t)b * NCHUNK + c) * NHEADS + h) * HEADDIM) * DSTATE;
        for (int i = 0; i < 8; ++i) {
            int idx = tid + i * 256;
            int p = idx >> 5, q = idx & 31;
            float4 v = *reinterpret_cast<const float4*>(&sb[(size_t)p * DSTATE + q * 4]);
            Ss[p][q*4+0] = v.x; Ss[p][q*4+1] = v.y; Ss[p][q*4+2] = v.z; Ss[p][q*4+3] = v.w;
        }
        if (tid < LCHUNK)
            ea[tid] = __expf(acsbuf[(((size_t)b * NCHUNK + c) * NHEADS + h) * LCHUNK + tid]);
        __syncthreads();
        float acc[4][4] = {};
        for (int n = 0; n < DSTATE; ++n) {
            float cv[4], sv[4];
            #pragma unroll
            for (int i = 0; i < 4; ++i) cv[i] = Cs[ty*4+i][n];
            #pragma unroll
            for (int j = 0; j < 4; ++j) sv[j] = Ss[tx*4+j][n];
            #pragma unroll
            for (int i = 0; i < 4; ++i)
                #pragma unroll
                for (int j = 0; j < 4; ++j) acc[i][j] += cv[i]*sv[j];
        }
        #pragma unroll
        for (int i = 0; i < 4; ++i) {
            int l = ty*4+i;
            #pragma unroll
            for (int j = 0; j < 4; ++j) {
                int p = tx*4+j;
                ybuf[(size_t)(row0 + l) * DINNER + h * HEADDIM + p] += acc[i][j] * ea[l];
            }
        }
    }
}

// ----------------------------------------- gate (silu(z)) + RMSNorm in place
__global__ __launch_bounds__(256) void gate_norm_k(float* __restrict__ ybuf,
                                                   const float* __restrict__ zx,
                                                   const float* __restrict__ nw) {
    const int row  = blockIdx.x * 4 + (threadIdx.x >> 6);
    const int lane = threadIdx.x & 63;
    float g[8];
    float ss = 0.f;
    #pragma unroll
    for (int j = 0; j < 8; ++j) {
        int cidx = j * 64 + lane;
        float y = ybuf[(size_t)row * DINNER + cidx];
        float z = zx[(size_t)row * ZXLD + cidx];
        float sz = z / (1.f + __expf(-z));
        g[j] = y * sz;
        ss += g[j] * g[j];
    }
    #pragma unroll
    for (int off = 32; off; off >>= 1) ss += __shfl_xor(ss, off);
    float r = rsqrtf(ss / (float)DINNER + EPSV);
    #pragma unroll
    for (int j = 0; j < 8; ++j) {
        int cidx = j * 64 + lane;
        ybuf[(size_t)row * DINNER + cidx] = g[j] * r * nw[cidx];
    }
}

// ---------------------------------------------------------------- launch
extern "C" void kernel_launch(void* const* d_in, const int* in_sizes, int n_in,
                              void* d_out, int out_size, void* d_ws, size_t ws_size,
                              hipStream_t stream) {
    const float* u       = (const float*)d_in[0];
    const float* W_in    = (const float*)d_in[1];
    const float* conv_w  = (const float*)d_in[2];
    const float* conv_b  = (const float*)d_in[3];
    const float* dt_bias = (const float*)d_in[4];
    const float* A_log   = (const float*)d_in[5];
    const float* Dp      = (const float*)d_in[6];
    const float* norm_w  = (const float*)d_in[7];
    const float* W_out   = (const float*)d_in[8];
    float* out = (float*)d_out;

    char* p = (char*)d_ws;
    float*  zx       = (float*)p;  p += (size_t)ROWS * ZXLD * sizeof(float);     // 83.9 MB
    float*  xbc      = (float*)p;  p += (size_t)ROWS * CONVDIM * sizeof(float);  // 50.3 MB
    float*  dtb      = (float*)p;  p += (size_t)ROWS * NHEADS  * sizeof(float);
    float*  adtb     = (float*)p;  p += (size_t)ROWS * NHEADS  * sizeof(float);
    float*  chunksum = (float*)p;  p += (size_t)BATCHN * NCHUNK * NHEADS * sizeof(float);
    float*  acsbuf   = (float*)p;  p += (size_t)BATCHN * NCHUNK * NHEADS * LCHUNK * sizeof(float);
    float*  states   = (float*)p;  p += (size_t)BATCHN * NCHUNK * NHEADS * HEADDIM * DSTATE * sizeof(float); // 67 MB
    float*  ybuf     = (float*)p;  p += (size_t)ROWS * DINNER * sizeof(float);   // 33.5 MB
    ushort* WtA      = (ushort*)p; p += (size_t)ZXLD * DMODEL * sizeof(ushort);  // [1280][256] bf16
    ushort* WtB      = (ushort*)p; p += (size_t)DMODEL * DINNER * sizeof(ushort);// [256][512] bf16

    // 0. weight transpose+cast (tiny)
    transpose_cast_k<<<dim3(ZXLD/32, DMODEL/32), 256, 0, stream>>>(W_in,  WtA, DMODEL, DINPROJ, 0);
    transpose_cast_k<<<dim3(DMODEL/32, DINNER/32), 256, 0, stream>>>(W_out, WtB, DINNER, DMODEL, 0);
    // 1. in_proj (z + xBC cols only): zx = u @ W_in[:, :1280]   (MFMA bf16)
    gemm_bf16<<<dim3(ZXLD/128, ROWS/128), 256, 0, stream>>>(u, WtA, zx, ROWS, ZXLD, DMODEL);
    // 1b. dt path exact f32 (fused GEMV + softplus + *A)
    dt_fused_k<<<ROWS/32, 256, 0, stream>>>(u, W_in, dt_bias, A_log, dtb, adtb);
    // 2. depthwise conv + silu
    conv_silu_k<<<4096, 256, 0, stream>>>(zx, conv_w, conv_b, xbc);
    // 3. per-chunk SSD: Y_diag + D*x, chunk states
    ssd_chunk_k<<<dim3(NCHUNK, BATCHN), 256, 0, stream>>>(
        xbc, dtb, adtb, Dp, ybuf, states, acsbuf, chunksum);
    // 4. inter-chunk state scan
    scan_k<<<BATCHN*NHEADS, 256, 0, stream>>>(states, chunksum);
    // 5. Y_off += C @ S_prefix * exp(acs)
    yoff_k<<<dim3(NCHUNK, BATCHN), 256, 0, stream>>>(xbc, states, acsbuf, ybuf);
    // 6. gate + RMSNorm (in place on ybuf)
    gate_norm_k<<<ROWS/4, 256, 0, stream>>>(ybuf, zx, norm_w);
    // 7. out_proj: out = g @ W_out   (MFMA bf16)
    gemm_bf16<<<dim3(DMODEL/128, ROWS/128), 256, 0, stream>>>(ybuf, WtB, out, ROWS, DMODEL, DINNER);
}

// Round 3
// 212.609 us; speedup vs baseline: 2.7467x; 1.6381x over previous
//
#include <hip/hip_runtime.h>
#include <hip/hip_bf16.h>
#include <math.h>

#define BATCHN  16
#define SEQ     1024
#define DMODEL  256
#define DSTATE  128
#define HEADDIM 64
#define DINNER  512
#define NHEADS  8
#define CONVDIM 768
#define DINPROJ 1288
#define ZXLD    1280
#define KCONV   4
#define NCHUNK  16
#define LCHUNK  64
#define EPSV    1e-5f
#define ROWS    (BATCHN*SEQ)

typedef __attribute__((ext_vector_type(8))) __bf16 bf16x8;
typedef __attribute__((ext_vector_type(4))) float  f32x4;

__device__ inline ushort f2bf(float f) {
    union { float f; uint32_t u; } v; v.f = f;
    uint32_t r = v.u + 0x7fff + ((v.u >> 16) & 1);
    return (ushort)(r >> 16);
}
__device__ inline float bf2f(ushort u) {
    union { uint32_t u; float f; } v; v.u = ((uint32_t)u) << 16;
    return v.f;
}
__device__ inline uint4 pack8(float4 a, float4 b) {
    uint4 r;
    r.x = (uint32_t)f2bf(a.x) | ((uint32_t)f2bf(a.y) << 16);
    r.y = (uint32_t)f2bf(a.z) | ((uint32_t)f2bf(a.w) << 16);
    r.z = (uint32_t)f2bf(b.x) | ((uint32_t)f2bf(b.y) << 16);
    r.w = (uint32_t)f2bf(b.z) | ((uint32_t)f2bf(b.w) << 16);
    return r;
}

// ---------------------------------------------- W transpose + cast to bf16
__global__ __launch_bounds__(256) void transpose_cast_k(const float* __restrict__ src,
                                                        ushort* __restrict__ dst,
                                                        int K, int ldsrc, int col0) {
    __shared__ float Ts[32][33];
    const int tx = threadIdx.x & 31, ty = threadIdx.x >> 5;
    const int n0 = blockIdx.x * 32, k0 = blockIdx.y * 32;
    #pragma unroll
    for (int j = 0; j < 4; ++j) {
        int kl = ty * 4 + j;
        Ts[kl][tx] = src[(size_t)(k0 + kl) * ldsrc + col0 + n0 + tx];
    }
    __syncthreads();
    #pragma unroll
    for (int j = 0; j < 4; ++j) {
        int nl = ty * 4 + j;
        dst[(size_t)(n0 + nl) * K + k0 + tx] = f2bf(Ts[tx][nl]);
    }
}

// ------------------------------------------------------- bf16 MFMA GEMM
#define LDSW 40
__global__ __launch_bounds__(256) void gemm_bf16(const float* __restrict__ A,
                                                 const ushort* __restrict__ Bt,
                                                 float* __restrict__ C,
                                                 int M, int N, int K) {
    __shared__ ushort As[128 * LDSW];
    __shared__ ushort Bs[128 * LDSW];
    const int tid  = threadIdx.x;
    const int m0 = blockIdx.y * 128, n0 = blockIdx.x * 128;
    const int wid = tid >> 6, lane = tid & 63;
    const int wr = wid >> 1, wc = wid & 1;
    const int r = tid >> 1, kq = tid & 1;
    const int fr = lane & 15, kc = lane >> 4;

    f32x4 acc[4][4];
    #pragma unroll
    for (int i = 0; i < 4; ++i)
        #pragma unroll
        for (int j = 0; j < 4; ++j) acc[i][j] = (f32x4)0.f;

    for (int kt = 0; kt < K; kt += 32) {
        const float* ap = &A[(size_t)(m0 + r) * K + kt + kq * 16];
        float4 v0 = *(const float4*)(ap + 0);
        float4 v1 = *(const float4*)(ap + 4);
        float4 v2 = *(const float4*)(ap + 8);
        float4 v3 = *(const float4*)(ap + 12);
        *(uint4*)&As[r * LDSW + kq * 16]     = pack8(v0, v1);
        *(uint4*)&As[r * LDSW + kq * 16 + 8] = pack8(v2, v3);
        const ushort* bp = &Bt[(size_t)(n0 + r) * K + kt + kq * 16];
        *(uint4*)&Bs[r * LDSW + kq * 16]     = *(const uint4*)(bp);
        *(uint4*)&Bs[r * LDSW + kq * 16 + 8] = *(const uint4*)(bp + 8);
        __syncthreads();
        bf16x8 af[4], bfv[4];
        #pragma unroll
        for (int i = 0; i < 4; ++i) {
            af[i]  = *(const bf16x8*)&As[(wr * 64 + i * 16 + fr) * LDSW + kc * 8];
            bfv[i] = *(const bf16x8*)&Bs[(wc * 64 + i * 16 + fr) * LDSW + kc * 8];
        }
        #pragma unroll
        for (int i = 0; i < 4; ++i)
            #pragma unroll
            for (int j = 0; j < 4; ++j)
                acc[i][j] = __builtin_amdgcn_mfma_f32_16x16x32_bf16(af[i], bfv[j], acc[i][j], 0, 0, 0);
        __syncthreads();
    }
    #pragma unroll
    for (int i = 0; i < 4; ++i)
        #pragma unroll
        for (int j = 0; j < 4; ++j)
            #pragma unroll
            for (int q = 0; q < 4; ++q) {
                int rr = m0 + wr * 64 + i * 16 + (lane >> 4) * 4 + q;
                int cc = n0 + wc * 64 + j * 16 + (lane & 15);
                C[(size_t)rr * N + cc] = acc[i][j][q];
            }
}

// ------------------------------------------------- dt path: exact f32 GEMV
__global__ __launch_bounds__(256) void dt_fused_k(const float* __restrict__ u,
                                                  const float* __restrict__ W_in,
                                                  const float* __restrict__ dt_bias,
                                                  const float* __restrict__ A_log,
                                                  float* __restrict__ dtb,
                                                  float* __restrict__ adtb) {
    __shared__ float Ws[DMODEL][NHEADS];
    const int tid = threadIdx.x;
    #pragma unroll
    for (int j = 0; j < 8; ++j) {
        int idx = tid + j * 256;
        Ws[idx >> 3][idx & 7] = W_in[(size_t)(idx >> 3) * DINPROJ + 1280 + (idx & 7)];
    }
    __syncthreads();
    const int lane = tid & 63, w = tid >> 6;
    const int h = lane & 7;
    const int row = blockIdx.x * 32 + w * 8 + (lane >> 3);
    const float* up = &u[(size_t)row * DMODEL];
    float acc = 0.f;
    for (int k = 0; k < DMODEL; k += 4) {
        float4 uv = *(const float4*)(up + k);
        acc += uv.x * Ws[k][h] + uv.y * Ws[k+1][h] + uv.z * Ws[k+2][h] + uv.w * Ws[k+3][h];
    }
    float v = acc + dt_bias[h];
    float dt = (v > 20.f) ? v : log1pf(__expf(v));
    dtb [(size_t)row * NHEADS + h] = dt;
    adtb[(size_t)row * NHEADS + h] = dt * (-__expf(A_log[h]));
}

// ------------------------------------------------- depthwise conv + SiLU (bf16 out)
__global__ void conv_silu_k(const float* __restrict__ zx,
                            const float* __restrict__ cw,
                            const float* __restrict__ cb,
                            ushort* __restrict__ out) {
    int idx = blockIdx.x * blockDim.x + threadIdx.x;
    const int total = ROWS * CONVDIM;
    const int stride = gridDim.x * blockDim.x;
    for (; idx < total; idx += stride) {
        int c  = idx % CONVDIM;
        int bt = idx / CONVDIM;
        int t  = bt & (SEQ - 1);
        float acc = cb[c];
        #pragma unroll
        for (int k = 0; k < KCONV; ++k) {
            int tt = t - (KCONV - 1) + k;
            if (tt >= 0)
                acc += zx[(size_t)(bt - (KCONV - 1) + k) * ZXLD + DINNER + c]
                       * cw[c * KCONV + k];
        }
        out[idx] = f2bf(acc / (1.f + __expf(-acc)));
    }
}

// -------------------------------------------------- SSD MFMA kernel
// grid (c=16, b=16, hgrp=2), 256 threads, LDS ~55KB -> 2 blocks/CU.
#define SLDA 136   // Bs/Cs stride (ushorts), 272B = 17*16B
#define SLDB 72    // Ps/Xt/Xdt/Btr stride,   144B =  9*16B
__global__ __launch_bounds__(256) void ssd_mfma_k(const ushort* __restrict__ xbc,
                                                  const float* __restrict__ dtb,
                                                  const float* __restrict__ adtb,
                                                  const float* __restrict__ Dp,
                                                  float* __restrict__ ybuf,
                                                  float* __restrict__ states,
                                                  float* __restrict__ acsbuf,
                                                  float* __restrict__ chunksum) {
    const int c = blockIdx.x, b = blockIdx.y, hgrp = blockIdx.z;
    const int row0 = b * SEQ + c * LCHUNK;
    const int tid = threadIdx.x;
    const int lane = tid & 63, w = tid >> 6;
    const int fr = lane & 15, kc = lane >> 4;

    __shared__ union {
        struct { ushort Bs[64][SLDA]; ushort Cs[64][SLDA]; } p1;
        struct { ushort Ps[64][SLDB]; ushort Xt[64][SLDB]; ushort Xdt[64][SLDB]; } p2;
    } U;
    __shared__ ushort Btr[128][SLDB];   // B^T [n][l]
    __shared__ float acs4[4][64];
    __shared__ float dts[4][64];

    // per-head cumsum via wave Kogge-Stone: wave w handles head hgrp*4+w
    {
        const int hh = hgrp * 4 + w;
        float v = adtb[(size_t)(row0 + lane) * NHEADS + hh];
        #pragma unroll
        for (int off = 1; off < 64; off <<= 1) {
            float t = __shfl_up(v, off);
            if (lane >= off) v += t;
        }
        acs4[w][lane] = v;
        acsbuf[(((size_t)b * NCHUNK + c) * NHEADS + hh) * LCHUNK + lane] = v;
        if (lane == 63) chunksum[((size_t)b * NCHUNK + c) * NHEADS + hh] = v;
        dts[w][lane] = dtb[(size_t)(row0 + lane) * NHEADS + hh];
    }
    // stage B,C (bf16 direct) + B^T
    for (int it = 0; it < 4; ++it) {
        int idx = tid + it * 256;           // 1024: l(64) x ng(16)
        int l = idx >> 4, ng = idx & 15;
        const ushort* rp = &xbc[(size_t)(row0 + l) * CONVDIM + DINNER];
        uint4 vb = *(const uint4*)(rp + ng * 8);
        *(uint4*)&U.p1.Bs[l][ng * 8] = vb;
        uint4 vc = *(const uint4*)(rp + DSTATE + ng * 8);
        *(uint4*)&U.p1.Cs[l][ng * 8] = vc;
        const ushort* pv = (const ushort*)&vb;
        #pragma unroll
        for (int j = 0; j < 8; ++j) Btr[ng * 8 + j][l] = pv[j];
    }
    __syncthreads();

    // G quadrant per wave: rows wr*32.., cols wc*32..
    const int wr = w >> 1, wc = w & 1;
    f32x4 accG[2][2];
    #pragma unroll
    for (int i = 0; i < 2; ++i)
        #pragma unroll
        for (int j = 0; j < 2; ++j) accG[i][j] = (f32x4)0.f;
    #pragma unroll
    for (int kt = 0; kt < 4; ++kt) {
        bf16x8 af[2], bfv[2];
        #pragma unroll
        for (int i = 0; i < 2; ++i) af[i]  = *(const bf16x8*)&U.p1.Cs[wr*32 + i*16 + fr][kt*32 + kc*8];
        #pragma unroll
        for (int j = 0; j < 2; ++j) bfv[j] = *(const bf16x8*)&U.p1.Bs[wc*32 + j*16 + fr][kt*32 + kc*8];
        #pragma unroll
        for (int i = 0; i < 2; ++i)
            #pragma unroll
            for (int j = 0; j < 2; ++j)
                accG[i][j] = __builtin_amdgcn_mfma_f32_16x16x32_bf16(af[i], bfv[j], accG[i][j], 0, 0, 0);
    }
    __syncthreads();   // phase-1 LDS now dead

    for (int hl = 0; hl < 4; ++hl) {
        const int hh = hgrp * 4 + hl;
        const float acsL = acs4[hl][63];
        const float dec_l = __expf(acsL - acs4[hl][lane]);
        const float dt_l  = dts[hl][lane];
        // build X^T, Xd^T  (lane = l, wave covers 16 p's)
        #pragma unroll
        for (int i = 0; i < 4; ++i) {
            int p0 = w * 16 + i * 4;
            ushort4 xv = *(const ushort4*)&xbc[(size_t)(row0 + lane) * CONVDIM + hh * HEADDIM + p0];
            float x0 = bf2f(xv.x) * dt_l, x1 = bf2f(xv.y) * dt_l;
            float x2 = bf2f(xv.z) * dt_l, x3 = bf2f(xv.w) * dt_l;
            U.p2.Xt [p0+0][lane] = f2bf(x0); U.p2.Xdt[p0+0][lane] = f2bf(x0 * dec_l);
            U.p2.Xt [p0+1][lane] = f2bf(x1); U.p2.Xdt[p0+1][lane] = f2bf(x1 * dec_l);
            U.p2.Xt [p0+2][lane] = f2bf(x2); U.p2.Xdt[p0+2][lane] = f2bf(x2 * dec_l);
            U.p2.Xt [p0+3][lane] = f2bf(x3); U.p2.Xdt[p0+3][lane] = f2bf(x3 * dec_l);
        }
        // build P quadrant (D/dt folded into diagonal)
        #pragma unroll
        for (int i = 0; i < 2; ++i)
            #pragma unroll
            for (int j = 0; j < 2; ++j)
                #pragma unroll
                for (int q = 0; q < 4; ++q) {
                    int l = wr*32 + i*16 + (lane >> 4)*4 + q;
                    int s = wc*32 + j*16 + fr;
                    float v = 0.f;
                    if (s < l)       v = accG[i][j][q] * __expf(acs4[hl][l] - acs4[hl][s]);
                    else if (s == l) v = accG[i][j][q] + Dp[hh] / dts[hl][l];
                    U.p2.Ps[l][s] = f2bf(v);
                }
        __syncthreads();
        // Y_diag: wave w -> l-rows [16w,16w+16)
        {
            f32x4 acc[4];
            #pragma unroll
            for (int j = 0; j < 4; ++j) acc[j] = (f32x4)0.f;
            #pragma unroll
            for (int kt = 0; kt < 2; ++kt) {
                bf16x8 af = *(const bf16x8*)&U.p2.Ps[w*16 + fr][kt*32 + kc*8];
                #pragma unroll
                for (int j = 0; j < 4; ++j) {
                    bf16x8 bfv = *(const bf16x8*)&U.p2.Xt[j*16 + fr][kt*32 + kc*8];
                    acc[j] = __builtin_amdgcn_mfma_f32_16x16x32_bf16(af, bfv, acc[j], 0, 0, 0);
                }
            }
            #pragma unroll
            for (int j = 0; j < 4; ++j)
                #pragma unroll
                for (int q = 0; q < 4; ++q) {
                    int l = w*16 + (lane >> 4)*4 + q;
                    int p = j*16 + fr;
                    ybuf[(size_t)(row0 + l) * DINNER + hh * HEADDIM + p] = acc[j][q];
                }
        }
        // states: wave w -> n-range [32w, 32w+32)
        {
            f32x4 acc2[4][2];
            #pragma unroll
            for (int mt = 0; mt < 4; ++mt)
                #pragma unroll
                for (int jt = 0; jt < 2; ++jt) acc2[mt][jt] = (f32x4)0.f;
            #pragma unroll
            for (int kt = 0; kt < 2; ++kt) {
                bf16x8 a4[4], b2[2];
                #pragma unroll
                for (int mt = 0; mt < 4; ++mt) a4[mt] = *(const bf16x8*)&U.p2.Xdt[mt*16 + fr][kt*32 + kc*8];
                #pragma unroll
                for (int jt = 0; jt < 2; ++jt) b2[jt] = *(const bf16x8*)&Btr[w*32 + jt*16 + fr][kt*32 + kc*8];
                #pragma unroll
                for (int mt = 0; mt < 4; ++mt)
                    #pragma unroll
                    for (int jt = 0; jt < 2; ++jt)
                        acc2[mt][jt] = __builtin_amdgcn_mfma_f32_16x16x32_bf16(a4[mt], b2[jt], acc2[mt][jt], 0, 0, 0);
            }
            float* sb = states + ((((size_t)b * NCHUNK + c) * NHEADS + hh) * HEADDIM) * DSTATE;
            #pragma unroll
            for (int mt = 0; mt < 4; ++mt)
                #pragma unroll
                for (int jt = 0; jt < 2; ++jt)
                    #pragma unroll
                    for (int q = 0; q < 4; ++q) {
                        int p = mt*16 + (lane >> 4)*4 + q;
                        int n = w*32 + jt*16 + fr;
                        sb[(size_t)p * DSTATE + n] = acc2[mt][jt][q];
                    }
        }
        __syncthreads();
    }
}

// ------------------------------------- inter-chunk sequential state scan
__global__ __launch_bounds__(256) void scan_k(float* __restrict__ states,
                                              const float* __restrict__ chunksum) {
    const int bid = blockIdx.x;          // B*H*4 = 512
    const int pq = bid & 3, h = (bid >> 2) & 7, b = bid >> 5;
    const int tid = threadIdx.x;
    float pref[8];
    #pragma unroll
    for (int k = 0; k < 8; ++k) pref[k] = 0.f;
    for (int c = 0; c < NCHUNK; ++c) {
        float* base = states + (((size_t)b * NCHUNK + c) * NHEADS + h) * (HEADDIM * DSTATE) + pq * 2048;
        float dec = __expf(chunksum[((size_t)b * NCHUNK + c) * NHEADS + h]);
        #pragma unroll
        for (int k = 0; k < 8; ++k) {
            int idx = tid + k * 256;
            float cur = base[idx];
            base[idx] = pref[k];
            pref[k] = dec * pref[k] + cur;
        }
    }
}

// ------------------------------------------------- Y_off += C @ S^T * ea  (MFMA)
__global__ __launch_bounds__(256) void yoff_mfma_k(const ushort* __restrict__ xbc,
                                                   const float* __restrict__ states,
                                                   const float* __restrict__ acsbuf,
                                                   float* __restrict__ ybuf) {
    const int c = blockIdx.x, b = blockIdx.y, hgrp = blockIdx.z;
    const int row0 = b * SEQ + c * LCHUNK;
    const int tid = threadIdx.x;
    const int lane = tid & 63, w = tid >> 6;
    const int fr = lane & 15, kc = lane >> 4;
    __shared__ ushort Csh[64][SLDA];
    __shared__ ushort Ssh[64][SLDA];
    __shared__ float eah[64];

    for (int it = 0; it < 4; ++it) {
        int idx = tid + it * 256;
        int l = idx >> 4, ng = idx & 15;
        *(uint4*)&Csh[l][ng * 8] =
            *(const uint4*)&xbc[(size_t)(row0 + l) * CONVDIM + DINNER + DSTATE + ng * 8];
    }
    for (int hl = 0; hl < 4; ++hl) {
        const int hh = hgrp * 4 + hl;
        const float* sb = states + ((((size_t)b * NCHUNK + c) * NHEADS + hh) * HEADDIM) * DSTATE;
        for (int it = 0; it < 8; ++it) {
            int idx = tid + it * 256;        // 2048: p(64) x ng(32)
            int p = idx >> 5, ng = idx & 31;
            float4 v = *(const float4*)&sb[(size_t)p * DSTATE + ng * 4];
            ushort4 sv;
            sv.x = f2bf(v.x); sv.y = f2bf(v.y); sv.z = f2bf(v.z); sv.w = f2bf(v.w);
            *(ushort4*)&Ssh[p][ng * 4] = sv;
        }
        if (tid < 64)
            eah[tid] = __expf(acsbuf[(((size_t)b * NCHUNK + c) * NHEADS + hh) * LCHUNK + tid]);
        __syncthreads();
        f32x4 acc[4];
        #pragma unroll
        for (int j = 0; j < 4; ++j) acc[j] = (f32x4)0.f;
        #pragma unroll
        for (int kt = 0; kt < 4; ++kt) {
            bf16x8 af = *(const bf16x8*)&Csh[w*16 + fr][kt*32 + kc*8];
            #pragma unroll
            for (int j = 0; j < 4; ++j) {
                bf16x8 bfv = *(const bf16x8*)&Ssh[j*16 + fr][kt*32 + kc*8];
                acc[j] = __builtin_amdgcn_mfma_f32_16x16x32_bf16(af, bfv, acc[j], 0, 0, 0);
            }
        }
        #pragma unroll
        for (int j = 0; j < 4; ++j)
            #pragma unroll
            for (int q = 0; q < 4; ++q) {
                int l = w*16 + (lane >> 4)*4 + q;
                int p = j*16 + fr;
                float* yp = &ybuf[(size_t)(row0 + l) * DINNER + hh * HEADDIM + p];
                *yp += acc[j][q] * eah[l];
            }
        __syncthreads();
    }
}

// ----------------------------------------- gate (silu(z)) + RMSNorm in place
__global__ __launch_bounds__(256) void gate_norm_k(float* __restrict__ ybuf,
                                                   const float* __restrict__ zx,
                                                   const float* __restrict__ nw) {
    const int row  = blockIdx.x * 4 + (threadIdx.x >> 6);
    const int lane = threadIdx.x & 63;
    float g[8];
    float ss = 0.f;
    #pragma unroll
    for (int j = 0; j < 8; ++j) {
        int cidx = j * 64 + lane;
        float y = ybuf[(size_t)row * DINNER + cidx];
        float z = zx[(size_t)row * ZXLD + cidx];
        float sz = z / (1.f + __expf(-z));
        g[j] = y * sz;
        ss += g[j] * g[j];
    }
    #pragma unroll
    for (int off = 32; off; off >>= 1) ss += __shfl_xor(ss, off);
    float r = rsqrtf(ss / (float)DINNER + EPSV);
    #pragma unroll
    for (int j = 0; j < 8; ++j) {
        int cidx = j * 64 + lane;
        ybuf[(size_t)row * DINNER + cidx] = g[j] * r * nw[cidx];
    }
}

// ---------------------------------------------------------------- launch
extern "C" void kernel_launch(void* const* d_in, const int* in_sizes, int n_in,
                              void* d_out, int out_size, void* d_ws, size_t ws_size,
                              hipStream_t stream) {
    const float* u       = (const float*)d_in[0];
    const float* W_in    = (const float*)d_in[1];
    const float* conv_w  = (const float*)d_in[2];
    const float* conv_b  = (const float*)d_in[3];
    const float* dt_bias = (const float*)d_in[4];
    const float* A_log   = (const float*)d_in[5];
    const float* Dp      = (const float*)d_in[6];
    const float* norm_w  = (const float*)d_in[7];
    const float* W_out   = (const float*)d_in[8];
    float* out = (float*)d_out;

    char* p = (char*)d_ws;
    float*  zx       = (float*)p;  p += (size_t)ROWS * ZXLD * sizeof(float);
    float*  ybuf     = (float*)p;  p += (size_t)ROWS * DINNER * sizeof(float);
    float*  states   = (float*)p;  p += (size_t)BATCHN * NCHUNK * NHEADS * HEADDIM * DSTATE * sizeof(float);
    ushort* xbc      = (ushort*)p; p += (size_t)ROWS * CONVDIM * sizeof(ushort);
    float*  dtb      = (float*)p;  p += (size_t)ROWS * NHEADS  * sizeof(float);
    float*  adtb     = (float*)p;  p += (size_t)ROWS * NHEADS  * sizeof(float);
    float*  chunksum = (float*)p;  p += (size_t)BATCHN * NCHUNK * NHEADS * sizeof(float);
    float*  acsbuf   = (float*)p;  p += (size_t)BATCHN * NCHUNK * NHEADS * LCHUNK * sizeof(float);
    ushort* WtA      = (ushort*)p; p += (size_t)ZXLD * DMODEL * sizeof(ushort);
    ushort* WtB      = (ushort*)p; p += (size_t)DMODEL * DINNER * sizeof(ushort);

    transpose_cast_k<<<dim3(ZXLD/32, DMODEL/32), 256, 0, stream>>>(W_in,  WtA, DMODEL, DINPROJ, 0);
    transpose_cast_k<<<dim3(DMODEL/32, DINNER/32), 256, 0, stream>>>(W_out, WtB, DINNER, DMODEL, 0);
    gemm_bf16<<<dim3(ZXLD/128, ROWS/128), 256, 0, stream>>>(u, WtA, zx, ROWS, ZXLD, DMODEL);
    dt_fused_k<<<ROWS/32, 256, 0, stream>>>(u, W_in, dt_bias, A_log, dtb, adtb);
    conv_silu_k<<<4096, 256, 0, stream>>>(zx, conv_w, conv_b, xbc);
    ssd_mfma_k<<<dim3(NCHUNK, BATCHN, 2), 256, 0, stream>>>(
        xbc, dtb, adtb, Dp, ybuf, states, acsbuf, chunksum);
    scan_k<<<BATCHN*NHEADS*4, 256, 0, stream>>>(states, chunksum);
    yoff_mfma_k<<<dim3(NCHUNK, BATCHN, 2), 256, 0, stream>>>(xbc, states, acsbuf, ybuf);
    gate_norm_k<<<ROWS/4, 256, 0, stream>>>(ybuf, zx, norm_w);
    gemm_bf16<<<dim3(DMODEL/128, ROWS/128), 256, 0, stream>>>(ybuf, WtB, out, ROWS, DMODEL, DINNER);
}